// Round 9
// baseline (43.016 us; speedup 1.0000x reference)
//
#include <hip/hip_runtime.h>
#include <math.h>

#define N_STATIONS 276
#define CTX 384
#define CTX4 96            // float4s per z row
#define TGT 96
#define BATCH 4096

#define HROWS 48           // rows per block (half of TGT)
#define MCH 32             // samples per chunk
#define KP 64              // k-panel width
#define NPANEL 6           // 384 / 64
#define WSTR 66            // W LDS row stride in floats (64 + 2 -> 2-way = free)
#define NBLK (N_STATIONS * 2)

// ---------- kernel 1: per-station sample lists (compact, no padding) ----------
__global__ __launch_bounds__(1024) void build_lists(
    const int* __restrict__ stations,
    int* __restrict__ order,    // (BATCH,)
    int* __restrict__ offsets)  // (N_STATIONS+1,)
{
    __shared__ int cnt[N_STATIONS];
    __shared__ int cnt2[N_STATIONS];
    __shared__ int poff[N_STATIONS + 1];
    const int tid = threadIdx.x;
    for (int i = tid; i < N_STATIONS; i += 1024) { cnt[i] = 0; cnt2[i] = 0; }
    __syncthreads();
    for (int b = tid; b < BATCH; b += 1024) atomicAdd(&cnt[stations[b]], 1);
    __syncthreads();
    // wave-parallel inclusive scan over 5 chunks of 64
    if (tid < 64) {
        int run = 0;
        for (int base = 0; base < N_STATIONS; base += 64) {
            const int i = base + tid;
            int v = (i < N_STATIONS) ? cnt[i] : 0;
#pragma unroll
            for (int off = 1; off < 64; off <<= 1) {
                int u = __shfl_up(v, off, 64);
                if (tid >= off) v += u;
            }
            if (i < N_STATIONS) poff[i + 1] = run + v;
            run += __shfl(v, 63, 64);
        }
        if (tid == 0) poff[0] = 0;
    }
    __syncthreads();
    for (int b = tid; b < BATCH; b += 1024) {
        int s = stations[b];
        int p = atomicAdd(&cnt2[s], 1);
        order[poff[s] + p] = b;          // within-station order irrelevant to outputs
    }
    if (tid <= N_STATIONS) offsets[tid] = poff[tid];
}

// ---------- kernel 2: one block per (station x row-half), W once via LDS ----------
// 256 thr: rg = tid&15 (row-group), sg = tid>>4 (sample-pair).
// Thread tile: samples {2sg, 2sg+1}, rows {rg, rg+16, rg+32} of this half.
// W: double-buffered K-panels (48 x 64 f32, stride-66 LDS rows) streamed from HBM once.
// z: chunk of <=32 samples, full K, normalized at stage time, broadcast reads.
__global__ __launch_bounds__(256) void nlinear_lds(
    const float* __restrict__ z,        // (BATCH, CTX)
    const int*   __restrict__ order,
    const int*   __restrict__ offsets,
    const float* __restrict__ W,        // (N_STATIONS, TGT, CTX)
    const float* __restrict__ bias,     // (N_STATIONS, TGT)
    const float* __restrict__ loc,
    const float* __restrict__ scale,
    float*       __restrict__ out)      // (BATCH, TGT)
{
    __shared__ float zl[MCH * CTX];           // 49152 B
    __shared__ float wl[2][HROWS * WSTR];     // 2 x 12672 B  (total 74.5 KB)

    const int bid = blockIdx.x;
    const int s = bid >> 1;
    const int h = bid & 1;

    const int start = offsets[s];
    const int m = offsets[s + 1] - start;
    if (m == 0) return;

    const int tid = threadIdx.x;
    const int rg = tid & 15;
    const int sg = tid >> 4;

    const float lc = loc[s], sc = scale[s], inv = 1.0f / sc;

    const float4* z4  = reinterpret_cast<const float4*>(z);
    const float4* w4g = reinterpret_cast<const float4*>(W)
                      + ((size_t)s * TGT + h * HROWS) * CTX4;  // this half's rows

    // hoist bias for this thread's 3 rows
    float br[3];
#pragma unroll
    for (int r = 0; r < 3; ++r)
        br[r] = bias[(size_t)s * TGT + h * HROWS + rg + 16 * r];

    for (int c0 = 0; c0 < m; c0 += MCH) {
        const int mch = min(MCH, m - c0);

        __syncthreads();   // previous chunk fully consumed before restaging zl

        // ---- stage normalized z chunk -> LDS (coalesced float4) ----
        for (int q = tid; q < mch * CTX4; q += 256) {
            int j  = q / CTX4;
            int kq = q - j * CTX4;
            float4 v = z4[(size_t)order[start + c0 + j] * CTX4 + kq];
            float4 vn = {(v.x - lc) * inv, (v.y - lc) * inv,
                         (v.z - lc) * inv, (v.w - lc) * inv};
            *reinterpret_cast<float4*>(&zl[j * CTX + kq * 4]) = vn;
        }

        // ---- prologue: panel 0 -> regs (3 float4/thread: q3 = tid + 256j) ----
        float4 wreg[3];
#pragma unroll
        for (int j = 0; j < 3; ++j) {
            int q3 = tid + 256 * j;
            int row = q3 >> 4, kq = q3 & 15;
            wreg[j] = w4g[(size_t)row * CTX4 + kq];     // panel 0: +0*16
        }

        float acc[3][2] = {{0.f,0.f},{0.f,0.f},{0.f,0.f}};
        __syncthreads();   // zl visible

        const bool act = (2 * sg < mch);

        for (int p = 0; p < NPANEL; ++p) {
            // write staged panel regs -> wl[p&1] (stride-66 rows; two float2 per f4)
            float* wb = wl[p & 1];
#pragma unroll
            for (int j = 0; j < 3; ++j) {
                int q3 = tid + 256 * j;
                int row = q3 >> 4, kq = q3 & 15;
                float2* d = reinterpret_cast<float2*>(&wb[row * WSTR + kq * 4]);
                d[0] = make_float2(wreg[j].x, wreg[j].y);
                d[1] = make_float2(wreg[j].z, wreg[j].w);
            }
            __syncthreads();   // panel p visible

            // issue next panel's global loads (hides HBM under compute)
            if (p + 1 < NPANEL) {
#pragma unroll
                for (int j = 0; j < 3; ++j) {
                    int q3 = tid + 256 * j;
                    int row = q3 >> 4, kq = q3 & 15;
                    wreg[j] = w4g[(size_t)row * CTX4 + (p + 1) * 16 + kq];
                }
            }

            if (act) {
                const float2* wl2 = reinterpret_cast<const float2*>(wb);
                const float2* zl2 = reinterpret_cast<const float2*>(zl);
                const int za0 = (2 * sg)     * (CTX / 2) + p * (KP / 2);
                const int zb0 = (2 * sg + 1) * (CTX / 2) + p * (KP / 2);
                const int w0b = (rg)      * (WSTR / 2);
                const int w1b = (rg + 16) * (WSTR / 2);
                const int w2b = (rg + 32) * (WSTR / 2);
#pragma unroll
                for (int k = 0; k < KP / 2; ++k) {
                    float2 w0 = wl2[w0b + k];
                    float2 w1 = wl2[w1b + k];
                    float2 w2 = wl2[w2b + k];
                    float2 za = zl2[za0 + k];
                    float2 zb = zl2[zb0 + k];
                    acc[0][0] += w0.x * za.x + w0.y * za.y;
                    acc[1][0] += w1.x * za.x + w1.y * za.y;
                    acc[2][0] += w2.x * za.x + w2.y * za.y;
                    acc[0][1] += w0.x * zb.x + w0.y * zb.y;
                    acc[1][1] += w1.x * zb.x + w1.y * zb.y;
                    acc[2][1] += w2.x * zb.x + w2.y * zb.y;
                }
            }
            __syncthreads();   // compute done before next ds_write overwrites other buf
        }

        // ---- epilogue: denorm + softplus + coalesced store ----
#pragma unroll
        for (int si = 0; si < 2; ++si) {
            int j = 2 * sg + si;
            if (c0 + j < m) {
                const int id = order[start + c0 + j];
#pragma unroll
                for (int r = 0; r < 3; ++r) {
                    const int row = h * HROWS + rg + 16 * r;
                    float v = (acc[r][si] + br[r]) * sc + lc;
                    out[(size_t)id * TGT + row] =
                        fmaxf(v, 0.f) + log1pf(expf(-fabsf(v)));
                }
            }
        }
    }
}

extern "C" void kernel_launch(void* const* d_in, const int* in_sizes, int n_in,
                              void* d_out, int out_size, void* d_ws, size_t ws_size,
                              hipStream_t stream) {
    const float* z        = (const float*)d_in[0];
    const int*   stations = (const int*)  d_in[1];
    const float* W        = (const float*)d_in[2];
    const float* bias     = (const float*)d_in[3];
    const float* loc      = (const float*)d_in[4];
    const float* scale    = (const float*)d_in[5];
    float* out = (float*)d_out;

    int* order   = (int*)d_ws;
    int* offsets = order + BATCH;

    build_lists<<<1, 1024, 0, stream>>>(stations, order, offsets);
    nlinear_lds<<<NBLK, 256, 0, stream>>>(z, order, offsets, W, bias, loc, scale, out);
}

// Round 10
// 32.371 us; speedup vs baseline: 1.3288x; 1.3288x over previous
//
#include <hip/hip_runtime.h>
#include <math.h>

#define N_STATIONS 276
#define CTX 384
#define TGT 96
#define BATCH 4096
#define NTILE_N 6                      // 96 cols / 16
#define NBLK (N_STATIONS * NTILE_N)    // 1656 one-wave blocks

typedef __attribute__((ext_vector_type(8))) short bf16x8;   // 8 bf16 (4 VGPRs)
typedef __attribute__((ext_vector_type(4))) float f32x4;    // MFMA acc

__device__ __forceinline__ short f2bf(float f) {            // RNE float->bf16
    unsigned u = __builtin_bit_cast(unsigned, f);
    u = (u + 0x7FFFu + ((u >> 16) & 1u)) >> 16;
    return (short)u;
}
__device__ __forceinline__ float bf2f(short h) {
    unsigned u = ((unsigned)(unsigned short)h) << 16;
    return __builtin_bit_cast(float, u);
}

// ---------- kernel 1: per-station sample lists (compact) ----------
__global__ __launch_bounds__(1024) void build_lists(
    const int* __restrict__ stations,
    int* __restrict__ order,    // (BATCH,)
    int* __restrict__ offsets)  // (N_STATIONS+1,)
{
    __shared__ int cnt[N_STATIONS];
    __shared__ int cnt2[N_STATIONS];
    __shared__ int poff[N_STATIONS + 1];
    const int tid = threadIdx.x;
    for (int i = tid; i < N_STATIONS; i += 1024) { cnt[i] = 0; cnt2[i] = 0; }
    __syncthreads();
    for (int b = tid; b < BATCH; b += 1024) atomicAdd(&cnt[stations[b]], 1);
    __syncthreads();
    if (tid < 64) {   // wave-parallel inclusive scan, 5 chunks of 64
        int run = 0;
        for (int base = 0; base < N_STATIONS; base += 64) {
            const int i = base + tid;
            int v = (i < N_STATIONS) ? cnt[i] : 0;
#pragma unroll
            for (int off = 1; off < 64; off <<= 1) {
                int u = __shfl_up(v, off, 64);
                if (tid >= off) v += u;
            }
            if (i < N_STATIONS) poff[i + 1] = run + v;
            run += __shfl(v, 63, 64);
        }
        if (tid == 0) poff[0] = 0;
    }
    __syncthreads();
    for (int b = tid; b < BATCH; b += 1024) {
        int s = stations[b];
        int p = atomicAdd(&cnt2[s], 1);
        order[poff[s] + p] = b;          // within-station order irrelevant to outputs
    }
    if (tid <= N_STATIONS) offsets[tid] = poff[tid];
}

// float4-pair -> bf16x8 hi + lo (exact W = hi + lo to ~2^-18 rel)
__device__ __forceinline__ void cvt_hilo(float4 a, float4 b, bf16x8& hi, bf16x8& lo) {
    float f[8] = {a.x, a.y, a.z, a.w, b.x, b.y, b.z, b.w};
#pragma unroll
    for (int i = 0; i < 8; ++i) {
        short h = f2bf(f[i]);
        hi[i] = h;
        lo[i] = f2bf(f[i] - bf2f(h));
    }
}
// float4-pair -> normalized bf16x8 (z path)
__device__ __forceinline__ bf16x8 cvt_norm(float4 a, float4 b, float lc, float inv) {
    float f[8] = {a.x, a.y, a.z, a.w, b.x, b.y, b.z, b.w};
    bf16x8 r;
#pragma unroll
    for (int i = 0; i < 8; ++i) r[i] = f2bf((f[i] - lc) * inv);
    return r;
}

// ---------- kernel 2: one wave per (station x 16-col tile), MFMA ----------
// D(16 samples x 16 cols) += A(16x32) * B(32x16) over 12 K-steps.
// A: zn rows (lane&15 = sample, 8 contig k). B: W rows (lane&15 = col, 8 contig k).
// W read ONCE from HBM; split hi/lo bf16 for precision (z-quant error dominates, ~0.02).
__global__ __launch_bounds__(64) void nlinear_mfma(
    const float* __restrict__ z,        // (BATCH, CTX)
    const int*   __restrict__ order,
    const int*   __restrict__ offsets,
    const float* __restrict__ W,        // (N_STATIONS, TGT, CTX)
    const float* __restrict__ bias,     // (N_STATIONS, TGT)
    const float* __restrict__ loc,
    const float* __restrict__ scale,
    float*       __restrict__ out)      // (BATCH, TGT)
{
    const int bid = blockIdx.x;
    const int s   = bid / NTILE_N;
    const int nt  = bid - s * NTILE_N;
    const int n0  = nt * 16;

    const int start = offsets[s];
    const int m     = offsets[s + 1] - start;
    if (m == 0) return;

    const int l  = threadIdx.x;       // 0..63
    const int lr = l & 15;
    const int kh = (l >> 4) * 8;      // lane's k sub-offset within a K=32 step

    const float lc = loc[s], sc = scale[s], inv = 1.0f / sc;

    const float* wrow  = W + ((size_t)s * TGT + n0 + lr) * CTX + kh;
    const float  biasv = bias[(size_t)s * TGT + n0 + lr];

    const int ntiles = (m + 15) >> 4;
    const int rbase  = (l >> 4) * 4;  // D row base for this lane

    for (int t0 = 0; t0 < ntiles; t0 += 2) {
        int j0 = t0 * 16 + lr;        if (j0 > m - 1) j0 = m - 1;
        int j1 = t0 * 16 + 16 + lr;   if (j1 > m - 1) j1 = m - 1;
        const float* zr0 = z + (size_t)order[start + j0] * CTX + kh;
        const float* zr1 = z + (size_t)order[start + j1] * CTX + kh;
        const bool two = (t0 + 1 < ntiles);

        f32x4 acc0 = {0.f, 0.f, 0.f, 0.f};
        f32x4 acc1 = {0.f, 0.f, 0.f, 0.f};

#pragma unroll
        for (int kk = 0; kk < 12; ++kk) {
            const int ko = kk * 32;
            float4 wv0 = *reinterpret_cast<const float4*>(wrow + ko);
            float4 wv1 = *reinterpret_cast<const float4*>(wrow + ko + 4);
            float4 a00 = *reinterpret_cast<const float4*>(zr0 + ko);
            float4 a01 = *reinterpret_cast<const float4*>(zr0 + ko + 4);

            bf16x8 bhi, blo;
            cvt_hilo(wv0, wv1, bhi, blo);
            bf16x8 afr0 = cvt_norm(a00, a01, lc, inv);

            acc0 = __builtin_amdgcn_mfma_f32_16x16x32_bf16(afr0, bhi, acc0, 0, 0, 0);
            acc0 = __builtin_amdgcn_mfma_f32_16x16x32_bf16(afr0, blo, acc0, 0, 0, 0);

            if (two) {
                float4 a10 = *reinterpret_cast<const float4*>(zr1 + ko);
                float4 a11 = *reinterpret_cast<const float4*>(zr1 + ko + 4);
                bf16x8 afr1 = cvt_norm(a10, a11, lc, inv);
                acc1 = __builtin_amdgcn_mfma_f32_16x16x32_bf16(afr1, bhi, acc1, 0, 0, 0);
                acc1 = __builtin_amdgcn_mfma_f32_16x16x32_bf16(afr1, blo, acc1, 0, 0, 0);
            }
        }

        // epilogue: D[row=(l>>4)*4+r][col=lr]; denorm + softplus, guarded by m
#pragma unroll
        for (int r = 0; r < 4; ++r) {
            int j = t0 * 16 + rbase + r;
            if (j < m) {
                int id = order[start + j];
                float v = (acc0[r] + biasv) * sc + lc;
                out[(size_t)id * TGT + n0 + lr] =
                    fmaxf(v, 0.f) + log1pf(expf(-fabsf(v)));
            }
        }
        if (two) {
#pragma unroll
            for (int r = 0; r < 4; ++r) {
                int j = t0 * 16 + 16 + rbase + r;
                if (j < m) {
                    int id = order[start + j];
                    float v = (acc1[r] + biasv) * sc + lc;
                    out[(size_t)id * TGT + n0 + lr] =
                        fmaxf(v, 0.f) + log1pf(expf(-fabsf(v)));
                }
            }
        }
    }
}

extern "C" void kernel_launch(void* const* d_in, const int* in_sizes, int n_in,
                              void* d_out, int out_size, void* d_ws, size_t ws_size,
                              hipStream_t stream) {
    const float* z        = (const float*)d_in[0];
    const int*   stations = (const int*)  d_in[1];
    const float* W        = (const float*)d_in[2];
    const float* bias     = (const float*)d_in[3];
    const float* loc      = (const float*)d_in[4];
    const float* scale    = (const float*)d_in[5];
    float* out = (float*)d_out;

    int* order   = (int*)d_ws;
    int* offsets = order + BATCH;

    build_lists<<<1, 1024, 0, stream>>>(stations, order, offsets);
    nlinear_mfma<<<NBLK, 64, 0, stream>>>(z, order, offsets, W, bias, loc, scale, out);
}